// Round 6
// baseline (152.585 us; speedup 1.0000x reference)
//
#include <hip/hip_runtime.h>

// R6: 4 rows per WG (grid 1024 x 256 thr; 4 WGs/CU, all resident).
// Attacks the ~40us plateau = per-WG cold-start latency serialization:
//  - all 4 lengths loaded once up front (scalar), no per-row length stall
//  - row r+1 global loads PRE-ISSUED (registers) under row r compute
//  - first-layer weights / biases loaded once per WG, reused 4x
//  - fc1 batched over 4 rows: 32 w_fc1 loads amortized 4x (per-WG w_fc1
//    traffic 32KB -> 8KB)
//  - hist zeroing folded into its readers (embedding phase) -> 3 barriers/row
// Keeps R3-R5 algebra: histogram-weighted table sums, register sums for
// binary vocabs, pool<->32x32-matmul commutation.

#define BDIM 256
#define RPB 4

struct RowRegs {
    float p0, p1, p2, c0, c1;
    int   k0, k1, k2, k3, k4, q0, q1;
};

__device__ __forceinline__ RowRegs load_row(const float* gp, const float* gc,
                                            const int* kp, const int* kc,
                                            int tid, int L) {
    RowRegs r;
    const int n3 = 3 * L, n2 = 2 * L, n5 = 5 * L;
    r.p0 = (tid       < n3) ? gp[tid]       : 0.f;
    r.p1 = (tid + 256 < n3) ? gp[tid + 256] : 0.f;
    r.p2 = (tid + 512 < n3) ? gp[tid + 512] : 0.f;
    r.c0 = (tid       < n2) ? gc[tid]       : 0.f;
    r.c1 = (tid + 256 < n2) ? gc[tid + 256] : 0.f;
    r.k0 = (tid        < n5) ? kp[tid]        : -1;
    r.k1 = (tid + 256  < n5) ? kp[tid + 256]  : -1;
    r.k2 = (tid + 512  < n5) ? kp[tid + 512]  : -1;
    r.k3 = (tid + 768  < n5) ? kp[tid + 768]  : -1;
    r.k4 = (tid + 1024 < n5) ? kp[tid + 1024] : -1;
    r.q0 = (tid       < n2) ? kc[tid]       : -1;
    r.q1 = (tid + 256 < n2) ? kc[tid + 256] : -1;
    return r;
}

__global__ __launch_bounds__(BDIM)
void mlpreg_kernel(const float* __restrict__ cont_p,
                   const float* __restrict__ cont_c,
                   const int* __restrict__ cat_p,
                   const int* __restrict__ cat_c,
                   const int* __restrict__ lengths,
                   const float* __restrict__ w_p1, const float* __restrict__ b_p1,
                   const float* __restrict__ w_p2, const float* __restrict__ b_p2,
                   const float* __restrict__ w_c1, const float* __restrict__ b_c1,
                   const float* __restrict__ w_c2, const float* __restrict__ b_c2,
                   const float* __restrict__ emb_g,  const float* __restrict__ emb_k,
                   const float* __restrict__ emb_pr, const float* __restrict__ emb_j,
                   const float* __restrict__ emb_r,  const float* __restrict__ emb_pl,
                   const float* __restrict__ emb_a,
                   const float* __restrict__ w_fc1, const float* __restrict__ b_fc1,
                   const float* __restrict__ w_fc2, const float* __restrict__ b_fc2,
                   float* __restrict__ out)
{
    constexpr int S = 256;
    __shared__ float sContP[S * 3];      // 3072 B
    __shared__ float sContC[S * 2];      // 2048 B
    __shared__ int   hist[2][96];        //  768 B  job@0(11) rep@11(34) place@45(19) add@64(31)
    __shared__ int   sBin[4][3];         //   48 B
    __shared__ float sRedP[128], sRedC[128];  // 1024 B
    __shared__ float sPacc[64];          //  256 B
    __shared__ float sPooled[RPB][128];  // 2048 B
    __shared__ float sF[4][RPB][64];     // 4096 B

    const int tid  = threadIdx.x;
    const int wv   = tid >> 6, lane = tid & 63;
    const int ch   = tid & 31, h = lane >> 5, g8 = tid >> 5;
    const int base = blockIdx.x * RPB;

    // ---- per-WG one-time setup ----
    int Ls[RPB];
    #pragma unroll
    for (int r = 0; r < RPB; ++r) {
        int L = lengths[base + r];
        Ls[r] = (L < 1) ? 1 : (L > S ? S : L);
    }
    const float* gpA[RPB]; const float* gcA[RPB];
    const int*   kpA[RPB]; const int*   kcA[RPB];
    #pragma unroll
    for (int r = 0; r < RPB; ++r) {
        gpA[r] = cont_p + (size_t)(base + r) * (S * 3);
        gcA[r] = cont_c + (size_t)(base + r) * (S * 2);
        kpA[r] = cat_p  + (size_t)(base + r) * (S * 5);
        kcA[r] = cat_c  + (size_t)(base + r) * (S * 2);
    }
    // first-layer weights in registers, loaded ONCE per WG
    const float wp0 = w_p1[ch], wp1 = w_p1[32 + ch], wp2 = w_p1[64 + ch], bp = b_p1[ch];
    const float wc0 = w_c1[ch], wc1 = w_c1[32 + ch], bc = b_c1[ch];

    for (int i = tid; i < 192; i += BDIM) ((int*)hist)[i] = 0;

    // prefetch row 0
    RowRegs cur = load_row(gpA[0], gcA[0], kpA[0], kcA[0], tid, Ls[0]);
    __syncthreads();   // hist zero visible

    #pragma unroll
    for (int r = 0; r < RPB; ++r) {
        const int   L    = Ls[r];
        const float Lf   = (float)L;
        const float invL = 1.0f / Lf;

        // ---- stage row r: cont -> LDS, cat -> hist/binary sums ----
        sContP[tid]       = cur.p0;
        sContP[tid + 256] = cur.p1;
        sContP[tid + 512] = cur.p2;
        sContC[tid]       = cur.c0;
        sContC[tid + 256] = cur.c1;

        int sg = 0, sk = 0, spr = 0;
        int* hc = hist[wv >> 1];
        {   // slot j: flat index tid+256j, col = idx % 5
            int c0 = tid % 5;
            int c1 = (c0 + 1) % 5, c2 = (c0 + 2) % 5, c3 = (c0 + 3) % 5, c4 = (c0 + 4) % 5;
            int v;
            v = cur.k0; if (v >= 0) { if (c0 == 0) sg += v; else if (c0 == 1) sk += v; else if (c0 == 2) spr += v; else if (c0 == 3) atomicAdd(&hc[v], 1); else atomicAdd(&hc[11 + v], 1); }
            v = cur.k1; if (v >= 0) { if (c1 == 0) sg += v; else if (c1 == 1) sk += v; else if (c1 == 2) spr += v; else if (c1 == 3) atomicAdd(&hc[v], 1); else atomicAdd(&hc[11 + v], 1); }
            v = cur.k2; if (v >= 0) { if (c2 == 0) sg += v; else if (c2 == 1) sk += v; else if (c2 == 2) spr += v; else if (c2 == 3) atomicAdd(&hc[v], 1); else atomicAdd(&hc[11 + v], 1); }
            v = cur.k3; if (v >= 0) { if (c3 == 0) sg += v; else if (c3 == 1) sk += v; else if (c3 == 2) spr += v; else if (c3 == 3) atomicAdd(&hc[v], 1); else atomicAdd(&hc[11 + v], 1); }
            v = cur.k4; if (v >= 0) { if (c4 == 0) sg += v; else if (c4 == 1) sk += v; else if (c4 == 2) spr += v; else if (c4 == 3) atomicAdd(&hc[v], 1); else atomicAdd(&hc[11 + v], 1); }
        }
        if (cur.q0 >= 0) atomicAdd(&hc[((tid & 1) ? 64 : 45) + cur.q0], 1);
        if (cur.q1 >= 0) atomicAdd(&hc[((tid & 1) ? 64 : 45) + cur.q1], 1);
        #pragma unroll
        for (int d = 32; d; d >>= 1) {
            sg += __shfl_xor(sg, d); sk += __shfl_xor(sk, d); spr += __shfl_xor(spr, d);
        }
        if (lane == 0) { sBin[wv][0] = sg; sBin[wv][1] = sk; sBin[wv][2] = spr; }
        __syncthreads();   // B1: staging complete

        // ---- pre-issue row r+1 loads (fly under row r compute) ----
        RowRegs nxt;
        if (r + 1 < RPB)
            nxt = load_row(gpA[r + 1], gcA[r + 1], kpA[r + 1], kcA[r + 1], tid, Ls[r + 1]);

        // ---- token relu-MLP loop (8 half-wave token groups) ----
        float accP = 0.f, accC = 0.f;
        #pragma unroll 2
        for (int t = g8; t < L; t += 8) {
            float c0 = sContP[3 * t], c1 = sContP[3 * t + 1], c2 = sContP[3 * t + 2];
            float d0 = sContC[2 * t], d1 = sContC[2 * t + 1];
            accP += fmaxf(fmaf(c0, wp0, fmaf(c1, wp1, fmaf(c2, wp2, bp))), 0.f);
            accC += fmaxf(fmaf(d0, wc0, fmaf(d1, wc1, bc)), 0.f);
        }
        accP += __shfl_down(accP, 32);
        accC += __shfl_down(accC, 32);
        if (lane < 32) { sRedP[wv * 32 + ch] = accP; sRedC[wv * 32 + ch] = accC; }
        __syncthreads();   // B2

        // ---- phase A: wv0=ep, wv1=ec (then zero their hist bins); wv2/3=pacc ----
        if (wv == 0) {
            float sgT  = (float)(sBin[0][0] + sBin[1][0] + sBin[2][0] + sBin[3][0]);
            float skT  = (float)(sBin[0][1] + sBin[1][1] + sBin[2][1] + sBin[3][1]);
            float sprT = (float)(sBin[0][2] + sBin[1][2] + sBin[2][2] + sBin[3][2]);
            float s = 0.f;
            if (h == 0) {
                s  = fmaf(Lf - sgT,  emb_g[ch],  sgT  * emb_g[32 + ch]);
                s += fmaf(Lf - sprT, emb_pr[ch], sprT * emb_pr[32 + ch]);
                #pragma unroll
                for (int q = 0; q < 6; ++q)  s = fmaf((float)(hist[0][q] + hist[1][q]),           emb_j[q * 32 + ch], s);
                #pragma unroll
                for (int q = 0; q < 17; ++q) s = fmaf((float)(hist[0][11 + q] + hist[1][11 + q]), emb_r[q * 32 + ch], s);
            } else {
                s = fmaf(Lf - skT, emb_k[ch], skT * emb_k[32 + ch]);
                #pragma unroll
                for (int q = 6; q < 11; ++q)  s = fmaf((float)(hist[0][q] + hist[1][q]),           emb_j[q * 32 + ch], s);
                #pragma unroll
                for (int q = 17; q < 34; ++q) s = fmaf((float)(hist[0][11 + q] + hist[1][11 + q]), emb_r[q * 32 + ch], s);
            }
            s += __shfl_down(s, 32);
            if (h == 0) sPooled[r][ch] = s * (invL * 0.2f);
            // zero bins 0..44 (both copies) — this wave is their only reader
            if (lane < 45) { hist[0][lane] = 0; hist[1][lane] = 0; }
        } else if (wv == 1) {
            float s = 0.f;
            if (h == 0) {
                #pragma unroll
                for (int q = 0; q < 10; ++q) s = fmaf((float)(hist[0][45 + q] + hist[1][45 + q]), emb_pl[q * 32 + ch], s);
                #pragma unroll
                for (int q = 0; q < 16; ++q) s = fmaf((float)(hist[0][64 + q] + hist[1][64 + q]), emb_a[q * 32 + ch], s);
            } else {
                #pragma unroll
                for (int q = 10; q < 19; ++q) s = fmaf((float)(hist[0][45 + q] + hist[1][45 + q]), emb_pl[q * 32 + ch], s);
                #pragma unroll
                for (int q = 16; q < 31; ++q) s = fmaf((float)(hist[0][64 + q] + hist[1][64 + q]), emb_a[q * 32 + ch], s);
            }
            s += __shfl_down(s, 32);
            if (h == 0) sPooled[r][32 + ch] = s * (invL * 0.5f);
            if (lane < 51) { hist[0][45 + lane] = 0; hist[1][45 + lane] = 0; }
        } else if (wv == 2) {
            if (lane < 32)
                sPacc[ch] = (sRedP[ch] + sRedP[32 + ch] + sRedP[64 + ch] + sRedP[96 + ch]) * invL;
        } else {
            if (lane < 32)
                sPacc[32 + ch] = (sRedC[ch] + sRedC[32 + ch] + sRedC[64 + ch] + sRedC[96 + ch]) * invL;
        }
        __syncthreads();   // B3

        // ---- phase B: 32x32 second layers (wv2/3); others fall through ----
        if (wv == 2) {
            const int kb = h * 16;
            float v = (h == 0) ? b_p2[ch] : 0.f;
            #pragma unroll
            for (int k = 0; k < 16; ++k) v = fmaf(sPacc[kb + k], w_p2[(kb + k) * 32 + ch], v);
            v += __shfl_down(v, 32);
            if (h == 0) sPooled[r][64 + ch] = v;
        } else if (wv == 3) {
            const int kb = h * 16;
            float v = (h == 0) ? b_c2[ch] : 0.f;
            #pragma unroll
            for (int k = 0; k < 16; ++k) v = fmaf(sPacc[32 + kb + k], w_c2[(kb + k) * 32 + ch], v);
            v += __shfl_down(v, 32);
            if (h == 0) sPooled[r][96 + ch] = v;
        }
        if (r + 1 < RPB) cur = nxt;
        // next loop's staging writes (sCont/hist/sBin) don't alias phase-B
        // reads (sPacc/w/sPooled), and B1 orders everything else.
    }
    __syncthreads();   // BF0: all sPooled ready

    // ---- fc1 batched over 4 rows: o=tid&63, quarter q=tid>>6 ----
    {
        const int o = tid & 63, q = tid >> 6;
        const float* wk = w_fc1 + (size_t)(q * 32) * 64 + o;
        float a0 = 0.f, a1 = 0.f, a2 = 0.f, a3 = 0.f;
        #pragma unroll
        for (int k = 0; k < 32; ++k) {
            float w = wk[(size_t)k * 64];
            a0 = fmaf(sPooled[0][q * 32 + k], w, a0);
            a1 = fmaf(sPooled[1][q * 32 + k], w, a1);
            a2 = fmaf(sPooled[2][q * 32 + k], w, a2);
            a3 = fmaf(sPooled[3][q * 32 + k], w, a3);
        }
        sF[q][0][o] = a0; sF[q][1][o] = a1; sF[q][2][o] = a2; sF[q][3][o] = a3;
    }
    __syncthreads();   // BF1

    // ---- combine + fc2: wave wv handles row wv (r = tid>>6, o = tid&63) ----
    {
        const int o = lane;       // 0..63, row = wv
        float hv = b_fc1[o] + (sF[0][wv][o] + sF[1][wv][o])
                            + (sF[2][wv][o] + sF[3][wv][o]);
        hv = fmaxf(hv, 0.f);
        float p0 = hv * w_fc2[o * 2 + 0];
        float p1 = hv * w_fc2[o * 2 + 1];
        #pragma unroll
        for (int d = 32; d; d >>= 1) { p0 += __shfl_xor(p0, d); p1 += __shfl_xor(p1, d); }
        if (lane == 0) {
            float2 o2;
            o2.x = fmaxf(p0 + b_fc2[0], 0.f);
            o2.y = fmaxf(p1 + b_fc2[1], 0.f);
            *(float2*)&out[(size_t)(base + wv) * 2] = o2;
        }
    }
}

extern "C" void kernel_launch(void* const* d_in, const int* in_sizes, int n_in,
                              void* d_out, int out_size, void* d_ws, size_t ws_size,
                              hipStream_t stream) {
    const float* cont_p = (const float*)d_in[0];
    const float* cont_c = (const float*)d_in[1];
    const int*   cat_p  = (const int*)d_in[2];
    const int*   cat_c  = (const int*)d_in[3];
    const int*   lens   = (const int*)d_in[4];
    const float* w_p1   = (const float*)d_in[5];
    const float* b_p1   = (const float*)d_in[6];
    const float* w_p2   = (const float*)d_in[7];
    const float* b_p2   = (const float*)d_in[8];
    const float* w_c1   = (const float*)d_in[9];
    const float* b_c1   = (const float*)d_in[10];
    const float* w_c2   = (const float*)d_in[11];
    const float* b_c2   = (const float*)d_in[12];
    const float* emb_g  = (const float*)d_in[13];
    const float* emb_k  = (const float*)d_in[14];
    const float* emb_pr = (const float*)d_in[15];
    const float* emb_j  = (const float*)d_in[16];
    const float* emb_r  = (const float*)d_in[17];
    const float* emb_pl = (const float*)d_in[18];
    const float* emb_a  = (const float*)d_in[19];
    const float* w_fc1  = (const float*)d_in[20];
    const float* b_fc1  = (const float*)d_in[21];
    const float* w_fc2  = (const float*)d_in[22];
    const float* b_fc2  = (const float*)d_in[23];
    float* out = (float*)d_out;

    const int B = 4096;
    hipLaunchKernelGGL(mlpreg_kernel, dim3(B / RPB), dim3(BDIM), 0, stream,
                       cont_p, cont_c, cat_p, cat_c, lens,
                       w_p1, b_p1, w_p2, b_p2, w_c1, b_c1, w_c2, b_c2,
                       emb_g, emb_k, emb_pr, emb_j, emb_r, emb_pl, emb_a,
                       w_fc1, b_fc1, w_fc2, b_fc2, out);
}

// Round 7
// 149.758 us; speedup vs baseline: 1.0189x; 1.0189x over previous
//
#include <hip/hip_runtime.h>

// R7: two-kernel split.
// K1 (12288 WGs x 64 thr): per (row, task) — task0: index histogram -> ws;
//   task1: pooled relu(cont_p@W1) -> ws; task2: pooled relu(cont_c@W1) -> ws.
//   Short independent critical paths, massive TLP, no table reads.
// K2 (512 WGs x 256 thr, 8 rows/WG): embedding = hist(101) x T(101x32) matmul
//   with T staged in LDS ONCE per 8 rows; p2/c2 with register-preloaded
//   weights; fc1 with weight loads amortized over 2 rows; fc2 butterfly.
//   No dependent global-load->fma chains in the per-row math.
// Algebra from R3-R6 kept: histogram-weighted table sums; binary vocab counts
// as index sums; pooling commutes with the 32x32 second layers.

#define WS_PACC_OFF 0                    // 4096*64 floats
#define WS_HIST_OFF (4096 * 64)          // 4096*104 floats

__global__ __launch_bounds__(64)
void mlpreg_pool(const float* __restrict__ cont_p,
                 const float* __restrict__ cont_c,
                 const int* __restrict__ cat_p,
                 const int* __restrict__ cat_c,
                 const int* __restrict__ lengths,
                 const float* __restrict__ w_p1, const float* __restrict__ b_p1,
                 const float* __restrict__ w_c1, const float* __restrict__ b_c1,
                 float* __restrict__ ws)
{
    constexpr int S = 256;
    __shared__ float sT[S * 3];   // token staging (3L or 2L floats)
    __shared__ int   h[96];       // job@0(11) rep@11(34) place@45(19) add@64(31)

    const int bx   = blockIdx.x;
    const int task = bx % 3;
    const int b    = bx / 3;
    const int lane = threadIdx.x;

    int L = lengths[b];
    L = (L < 1) ? 1 : (L > S ? S : L);
    const float invL = 1.0f / (float)L;

    if (task == 0) {
        h[lane] = 0;
        if (lane + 64 < 96) h[lane + 64] = 0;
        __syncthreads();
        const int* kp = cat_p + (size_t)b * (S * 5);
        const int* kc = cat_c + (size_t)b * (S * 2);
        int sg = 0, sk = 0, spr = 0;
        for (int i = lane; i < 5 * L; i += 64) {
            int v = kp[i], col = i % 5;
            if      (col == 0) sg  += v;
            else if (col == 1) sk  += v;
            else if (col == 2) spr += v;
            else if (col == 3) atomicAdd(&h[v], 1);        // job
            else               atomicAdd(&h[11 + v], 1);   // rep
        }
        for (int i = lane; i < 2 * L; i += 64) {
            int v = kc[i];
            atomicAdd(&h[(i & 1) ? (64 + v) : (45 + v)], 1);  // add / place
        }
        #pragma unroll
        for (int d = 32; d; d >>= 1) {
            sg  += __shfl_xor(sg,  d);
            sk  += __shfl_xor(sk,  d);
            spr += __shfl_xor(spr, d);
        }
        __syncthreads();
        float* o = ws + WS_HIST_OFF + (size_t)b * 104;
        for (int i = lane; i < 95; i += 64) o[i] = (float)h[i];
        if (lane == 0) {
            o[95] = (float)sg; o[96] = (float)sk; o[97] = (float)spr;
            o[98] = (float)L;
        }
    } else if (task == 1) {
        const float* gp = cont_p + (size_t)b * (S * 3);
        for (int i = lane; i < 3 * L; i += 64) sT[i] = gp[i];
        const int ch = lane & 31, pr = lane >> 5;
        const float w0 = w_p1[ch], w1 = w_p1[32 + ch], w2 = w_p1[64 + ch],
                    bb = b_p1[ch];
        __syncthreads();
        float acc = 0.f;
        #pragma unroll 4
        for (int t = pr; t < L; t += 2) {
            float c0 = sT[3 * t], c1 = sT[3 * t + 1], c2 = sT[3 * t + 2];
            acc += fmaxf(fmaf(c0, w0, fmaf(c1, w1, fmaf(c2, w2, bb))), 0.f);
        }
        acc += __shfl_down(acc, 32);
        if (lane < 32) ws[WS_PACC_OFF + (size_t)b * 64 + ch] = acc * invL;
    } else {
        const float* gc = cont_c + (size_t)b * (S * 2);
        for (int i = lane; i < 2 * L; i += 64) sT[i] = gc[i];
        const int ch = lane & 31, pr = lane >> 5;
        const float w0 = w_c1[ch], w1 = w_c1[32 + ch], bb = b_c1[ch];
        __syncthreads();
        float acc = 0.f;
        #pragma unroll 4
        for (int t = pr; t < L; t += 2) {
            float d0 = sT[2 * t], d1 = sT[2 * t + 1];
            acc += fmaxf(fmaf(d0, w0, fmaf(d1, w1, bb)), 0.f);
        }
        acc += __shfl_down(acc, 32);
        if (lane < 32) ws[WS_PACC_OFF + (size_t)b * 64 + 32 + ch] = acc * invL;
    }
}

__global__ __launch_bounds__(256)
void mlpreg_head(const float* __restrict__ emb_g,  const float* __restrict__ emb_k,
                 const float* __restrict__ emb_pr, const float* __restrict__ emb_j,
                 const float* __restrict__ emb_r,  const float* __restrict__ emb_pl,
                 const float* __restrict__ emb_a,
                 const float* __restrict__ w_p2, const float* __restrict__ b_p2,
                 const float* __restrict__ w_c2, const float* __restrict__ b_c2,
                 const float* __restrict__ w_fc1, const float* __restrict__ b_fc1,
                 const float* __restrict__ w_fc2, const float* __restrict__ b_fc2,
                 const float* __restrict__ ws, float* __restrict__ out)
{
    // T rows: job@0(11) rep@11(34) place@45(19) add@64(31) g@95(2) k@97(2) pr@99(2)
    __shared__ float T[101 * 32];     // 12928 B
    __shared__ float hF[8][104];      //  3328 B
    __shared__ float pacc[8][64];     //  2048 B
    __shared__ float sPool[8][128];   //  4096 B
    __shared__ float sH[8][64];       //  2048 B

    const int tid   = threadIdx.x;
    const int rbase = blockIdx.x * 8;

    for (int i = tid; i < 11 * 32; i += 256) T[i]           = emb_j[i];
    for (int i = tid; i < 34 * 32; i += 256) T[11 * 32 + i] = emb_r[i];
    for (int i = tid; i < 19 * 32; i += 256) T[45 * 32 + i] = emb_pl[i];
    for (int i = tid; i < 31 * 32; i += 256) T[64 * 32 + i] = emb_a[i];
    for (int i = tid; i < 2 * 32;  i += 256) T[95 * 32 + i] = emb_g[i];
    for (int i = tid; i < 2 * 32;  i += 256) T[97 * 32 + i] = emb_k[i];
    for (int i = tid; i < 2 * 32;  i += 256) T[99 * 32 + i] = emb_pr[i];
    for (int i = tid; i < 8 * 104; i += 256)
        hF[i / 104][i % 104] = ws[WS_HIST_OFF + (size_t)(rbase + i / 104) * 104 + (i % 104)];
    for (int i = tid; i < 8 * 64; i += 256)
        pacc[i / 64][i % 64] = ws[WS_PACC_OFF + (size_t)(rbase + i / 64) * 64 + (i % 64)];
    __syncthreads();

    const int rr = tid >> 5, ch = tid & 31;
    {
        const float Lf = hF[rr][98], invL = 1.0f / Lf;
        const float sg = hF[rr][95], sk = hF[rr][96], spr = hF[rr][97];
        // binary-vocab terms directly from counts
        float sep = fmaf(Lf - sg,  T[95 * 32 + ch], sg  * T[96 * 32 + ch])
                  + fmaf(Lf - sk,  T[97 * 32 + ch], sk  * T[98 * 32 + ch])
                  + fmaf(Lf - spr, T[99 * 32 + ch], spr * T[100 * 32 + ch]);
        float sec = 0.f;
        #pragma unroll
        for (int r = 0; r < 45; ++r)  sep = fmaf(hF[rr][r], T[r * 32 + ch], sep);
        #pragma unroll
        for (int r = 45; r < 95; ++r) sec = fmaf(hF[rr][r], T[r * 32 + ch], sec);
        sPool[rr][ch]      = sep * (invL * 0.2f);
        sPool[rr][32 + ch] = sec * (invL * 0.5f);

        // p2 / c2: preload weight columns to registers, then LDS-fed fmas
        float wp[32], wc[32];
        #pragma unroll
        for (int k = 0; k < 32; ++k) wp[k] = w_p2[k * 32 + ch];
        #pragma unroll
        for (int k = 0; k < 32; ++k) wc[k] = w_c2[k * 32 + ch];
        float vp = b_p2[ch], vc = b_c2[ch];
        #pragma unroll
        for (int k = 0; k < 32; ++k) {
            vp = fmaf(pacc[rr][k],      wp[k], vp);
            vc = fmaf(pacc[rr][32 + k], wc[k], vc);
        }
        sPool[rr][64 + ch] = vp;
        sPool[rr][96 + ch] = vc;
    }
    __syncthreads();

    // fc1: lane = out o (0..63) x row-quarter rq (0..3); rows rq and rq+4
    {
        const int o = tid & 63, rq = tid >> 6;
        float x0 = 0.f, x1 = 0.f, y0 = 0.f, y1 = 0.f;
        #pragma unroll 8
        for (int k = 0; k < 128; k += 2) {
            float wa = w_fc1[(size_t)(k + 0) * 64 + o];
            float wb = w_fc1[(size_t)(k + 1) * 64 + o];
            x0 = fmaf(sPool[rq][k],         wa, x0);
            x1 = fmaf(sPool[rq][k + 1],     wb, x1);
            y0 = fmaf(sPool[rq + 4][k],     wa, y0);
            y1 = fmaf(sPool[rq + 4][k + 1], wb, y1);
        }
        const float bo = b_fc1[o];
        sH[rq][o]     = fmaxf(bo + x0 + x1, 0.f);
        sH[rq + 4][o] = fmaxf(bo + y0 + y1, 0.f);
    }
    __syncthreads();

    // fc2: lane = (rr, ch); each lane covers k = ch and ch+32; 32-lane reduce
    {
        float h0 = sH[rr][ch], h1 = sH[rr][32 + ch];
        float p0 = fmaf(h0, w_fc2[ch * 2 + 0], h1 * w_fc2[(32 + ch) * 2 + 0]);
        float p1 = fmaf(h0, w_fc2[ch * 2 + 1], h1 * w_fc2[(32 + ch) * 2 + 1]);
        #pragma unroll
        for (int d = 16; d; d >>= 1) {
            p0 += __shfl_xor(p0, d);
            p1 += __shfl_xor(p1, d);
        }
        if (ch == 0) {
            float2 o2;
            o2.x = fmaxf(p0 + b_fc2[0], 0.f);
            o2.y = fmaxf(p1 + b_fc2[1], 0.f);
            *(float2*)&out[(size_t)(rbase + rr) * 2] = o2;
        }
    }
}

extern "C" void kernel_launch(void* const* d_in, const int* in_sizes, int n_in,
                              void* d_out, int out_size, void* d_ws, size_t ws_size,
                              hipStream_t stream) {
    const float* cont_p = (const float*)d_in[0];
    const float* cont_c = (const float*)d_in[1];
    const int*   cat_p  = (const int*)d_in[2];
    const int*   cat_c  = (const int*)d_in[3];
    const int*   lens   = (const int*)d_in[4];
    const float* w_p1   = (const float*)d_in[5];
    const float* b_p1   = (const float*)d_in[6];
    const float* w_p2   = (const float*)d_in[7];
    const float* b_p2   = (const float*)d_in[8];
    const float* w_c1   = (const float*)d_in[9];
    const float* b_c1   = (const float*)d_in[10];
    const float* w_c2   = (const float*)d_in[11];
    const float* b_c2   = (const float*)d_in[12];
    const float* emb_g  = (const float*)d_in[13];
    const float* emb_k  = (const float*)d_in[14];
    const float* emb_pr = (const float*)d_in[15];
    const float* emb_j  = (const float*)d_in[16];
    const float* emb_r  = (const float*)d_in[17];
    const float* emb_pl = (const float*)d_in[18];
    const float* emb_a  = (const float*)d_in[19];
    const float* w_fc1  = (const float*)d_in[20];
    const float* b_fc1  = (const float*)d_in[21];
    const float* w_fc2  = (const float*)d_in[22];
    const float* b_fc2  = (const float*)d_in[23];
    float* out = (float*)d_out;
    float* ws  = (float*)d_ws;

    hipLaunchKernelGGL(mlpreg_pool, dim3(3 * 4096), dim3(64), 0, stream,
                       cont_p, cont_c, cat_p, cat_c, lens,
                       w_p1, b_p1, w_c1, b_c1, ws);
    hipLaunchKernelGGL(mlpreg_head, dim3(512), dim3(256), 0, stream,
                       emb_g, emb_k, emb_pr, emb_j, emb_r, emb_pl, emb_a,
                       w_p2, b_p2, w_c2, b_c2, w_fc1, b_fc1, w_fc2, b_fc2,
                       ws, out);
}

// Round 8
// 139.907 us; speedup vs baseline: 1.0906x; 1.0704x over previous
//
#include <hip/hip_runtime.h>

// R8: one 64-lane wave per WG, TWO rows per wave (grid 2048 x 64).
// Rationale: five prior structures all pinned at ~40us kernel ~= 2.4us/row
// = one row's serial load->use critical path. Here the expensive tail
// (emb-table weighted sum, p2/c2, fc1) loads every weight ONCE per 2 rows
// and feeds 2 independent accumulator chains (2x ILP, 2x fewer chained
// loads/row). No inter-wave coupling at all; 3 single-wave barriers.
// Algebra kept from R3-R7: histogram-weighted table sums, binary-vocab
// counts = index sums, pooling commutes with the 32x32 second layers.

#define BDIM 64

__global__ __launch_bounds__(BDIM)
void mlpreg_kernel(const float* __restrict__ cont_p,
                   const float* __restrict__ cont_c,
                   const int* __restrict__ cat_p,
                   const int* __restrict__ cat_c,
                   const int* __restrict__ lengths,
                   const float* __restrict__ w_p1, const float* __restrict__ b_p1,
                   const float* __restrict__ w_p2, const float* __restrict__ b_p2,
                   const float* __restrict__ w_c1, const float* __restrict__ b_c1,
                   const float* __restrict__ w_c2, const float* __restrict__ b_c2,
                   const float* __restrict__ emb_g,  const float* __restrict__ emb_k,
                   const float* __restrict__ emb_pr, const float* __restrict__ emb_j,
                   const float* __restrict__ emb_r,  const float* __restrict__ emb_pl,
                   const float* __restrict__ emb_a,
                   const float* __restrict__ w_fc1, const float* __restrict__ b_fc1,
                   const float* __restrict__ w_fc2, const float* __restrict__ b_fc2,
                   float* __restrict__ out)
{
    constexpr int S = 256;
    __shared__ float sP[2][S * 3];    // 6144 B
    __shared__ float sC[2][S * 2];    // 4096 B
    __shared__ int   hist[2][96];     //  768 B  job@0(11) rep@11(34) place@45(19) add@64(31)
    __shared__ float sPacc[2][64];    //  512 B
    __shared__ float sPool[2][128];   // 1024 B

    const int lane = threadIdx.x;
    const int b0 = blockIdx.x * 2, b1 = b0 + 1;

    int L0 = lengths[b0]; L0 = (L0 < 1) ? 1 : (L0 > S ? S : L0);
    int L1 = lengths[b1]; L1 = (L1 < 1) ? 1 : (L1 > S ? S : L1);
    const float L0f = (float)L0, L1f = (float)L1;
    const float invL0 = 1.0f / L0f, invL1 = 1.0f / L1f;

    // zero hist (same-wave LDS ordering protects the later atomics)
    { int i = lane;            ((int*)hist)[i] = 0;
      i += 64;                 ((int*)hist)[i] = 0;
      i += 64;                 ((int*)hist)[i] = 0; }

    const int ch = lane & 31, h = lane >> 5;
    // first-layer weights: issue early, used after staging
    const float wp0 = w_p1[ch], wp1 = w_p1[32 + ch], wp2 = w_p1[64 + ch], bp = b_p1[ch];
    const float wc0 = w_c1[ch], wc1 = w_c1[32 + ch], bc = b_c1[ch];

    // ---- stage both rows' cont features as one float4 burst ----
    {
        const float4* gp0 = (const float4*)(cont_p + (size_t)b0 * (S * 3));
        const float4* gp1 = (const float4*)(cont_p + (size_t)b1 * (S * 3));
        const float4* gc0 = (const float4*)(cont_c + (size_t)b0 * (S * 2));
        const float4* gc1 = (const float4*)(cont_c + (size_t)b1 * (S * 2));
        const int n0 = (3 * L0 + 3) >> 2, n1 = (3 * L1 + 3) >> 2;
        const int m0 = (2 * L0 + 3) >> 2, m1 = (2 * L1 + 3) >> 2;
        for (int i = lane; i < n0; i += 64) *(float4*)&sP[0][4 * i] = gp0[i];
        for (int i = lane; i < n1; i += 64) *(float4*)&sP[1][4 * i] = gp1[i];
        for (int i = lane; i < m0; i += 64) *(float4*)&sC[0][4 * i] = gc0[i];
        for (int i = lane; i < m1; i += 64) *(float4*)&sC[1][4 * i] = gc1[i];
    }

    // ---- categorical pass: per-lane whole tokens (no %5), int2 for cat_c ----
    int sg0 = 0, sk0 = 0, sp0 = 0, sg1 = 0, sk1 = 0, sp1 = 0;
    {
        const int*  kp0 = cat_p + (size_t)b0 * (S * 5);
        const int*  kp1 = cat_p + (size_t)b1 * (S * 5);
        const int2* kc0 = (const int2*)(cat_c + (size_t)b0 * (S * 2));
        const int2* kc1 = (const int2*)(cat_c + (size_t)b1 * (S * 2));
        #pragma unroll 2
        for (int t = lane; t < L0; t += 64) {
            int v0 = kp0[5 * t], v1 = kp0[5 * t + 1], v2 = kp0[5 * t + 2],
                v3 = kp0[5 * t + 3], v4 = kp0[5 * t + 4];
            int2 q = kc0[t];
            sg0 += v0; sk0 += v1; sp0 += v2;
            atomicAdd(&hist[0][v3], 1);
            atomicAdd(&hist[0][11 + v4], 1);
            atomicAdd(&hist[0][45 + q.x], 1);
            atomicAdd(&hist[0][64 + q.y], 1);
        }
        #pragma unroll 2
        for (int t = lane; t < L1; t += 64) {
            int v0 = kp1[5 * t], v1 = kp1[5 * t + 1], v2 = kp1[5 * t + 2],
                v3 = kp1[5 * t + 3], v4 = kp1[5 * t + 4];
            int2 q = kc1[t];
            sg1 += v0; sk1 += v1; sp1 += v2;
            atomicAdd(&hist[1][v3], 1);
            atomicAdd(&hist[1][11 + v4], 1);
            atomicAdd(&hist[1][45 + q.x], 1);
            atomicAdd(&hist[1][64 + q.y], 1);
        }
    }
    #pragma unroll
    for (int d = 32; d; d >>= 1) {
        sg0 += __shfl_xor(sg0, d); sk0 += __shfl_xor(sk0, d); sp0 += __shfl_xor(sp0, d);
        sg1 += __shfl_xor(sg1, d); sk1 += __shfl_xor(sk1, d); sp1 += __shfl_xor(sp1, d);
    }
    __syncthreads();   // B1: staging + hist complete

    // ---- token relu-MLP: half-wave h owns row h (LDS broadcast reads) ----
    {
        const int   Lr   = h ? L1 : L0;
        const float invr = h ? invL1 : invL0;
        const float* tp = sP[h];
        const float* tc = sC[h];
        float aP = 0.f, aC = 0.f;
        #pragma unroll 4
        for (int t = 0; t < Lr; ++t) {
            float c0 = tp[3 * t], c1 = tp[3 * t + 1], c2 = tp[3 * t + 2];
            float2 d2 = *(const float2*)&tc[2 * t];
            aP += fmaxf(fmaf(c0, wp0, fmaf(c1, wp1, fmaf(c2, wp2, bp))), 0.f);
            aC += fmaxf(fmaf(d2.x, wc0, fmaf(d2.y, wc1, bc)), 0.f);
        }
        sPacc[h][ch]      = aP * invr;
        sPacc[h][32 + ch] = aC * invr;
    }
    __syncthreads();   // B2: sPacc ready

    // ---- tail part 1: emb weighted sums + 32x32 second layers,
    //      every weight loaded once, FMA'd into both rows ----
    if (h == 0) {
        float g0 = emb_g[ch],  g1 = emb_g[32 + ch];
        float k0 = emb_k[ch],  k1 = emb_k[32 + ch];
        float p0 = emb_pr[ch], p1 = emb_pr[32 + ch];
        float fg0 = (float)sg0, fk0 = (float)sk0, fp0 = (float)sp0;
        float fg1 = (float)sg1, fk1 = (float)sk1, fp1 = (float)sp1;
        float A0 = fmaf(L0f - fg0, g0, fg0 * g1) + fmaf(L0f - fk0, k0, fk0 * k1)
                 + fmaf(L0f - fp0, p0, fp0 * p1);
        float A1 = fmaf(L1f - fg1, g0, fg1 * g1) + fmaf(L1f - fk1, k0, fk1 * k1)
                 + fmaf(L1f - fp1, p0, fp1 * p1);
        #pragma unroll
        for (int r = 0; r < 11; ++r) {
            float w = emb_j[r * 32 + ch];
            A0 = fmaf((float)hist[0][r], w, A0);
            A1 = fmaf((float)hist[1][r], w, A1);
        }
        #pragma unroll
        for (int r = 0; r < 34; ++r) {
            float w = emb_r[r * 32 + ch];
            A0 = fmaf((float)hist[0][11 + r], w, A0);
            A1 = fmaf((float)hist[1][11 + r], w, A1);
        }
        sPool[0][ch] = A0 * (invL0 * 0.2f);
        sPool[1][ch] = A1 * (invL1 * 0.2f);

        float v0 = b_p2[ch], v1 = v0;
        #pragma unroll
        for (int k = 0; k < 32; ++k) {
            float w = w_p2[k * 32 + ch];
            v0 = fmaf(sPacc[0][k], w, v0);
            v1 = fmaf(sPacc[1][k], w, v1);
        }
        sPool[0][64 + ch] = v0;
        sPool[1][64 + ch] = v1;
    } else {
        float A0 = 0.f, A1 = 0.f;
        #pragma unroll
        for (int r = 0; r < 19; ++r) {
            float w = emb_pl[r * 32 + ch];
            A0 = fmaf((float)hist[0][45 + r], w, A0);
            A1 = fmaf((float)hist[1][45 + r], w, A1);
        }
        #pragma unroll
        for (int r = 0; r < 31; ++r) {
            float w = emb_a[r * 32 + ch];
            A0 = fmaf((float)hist[0][64 + r], w, A0);
            A1 = fmaf((float)hist[1][64 + r], w, A1);
        }
        sPool[0][32 + ch] = A0 * (invL0 * 0.5f);
        sPool[1][32 + ch] = A1 * (invL1 * 0.5f);

        float v0 = b_c2[ch], v1 = v0;
        #pragma unroll
        for (int k = 0; k < 32; ++k) {
            float w = w_c2[k * 32 + ch];
            v0 = fmaf(sPacc[0][32 + k], w, v0);
            v1 = fmaf(sPacc[1][32 + k], w, v1);
        }
        sPool[0][96 + ch] = v0;
        sPool[1][96 + ch] = v1;
    }
    __syncthreads();   // B3: sPool ready

    // ---- fc1 (one output per lane, both rows) + fc2 butterfly ----
    {
        const int o = lane;
        float x0 = b_fc1[o], y0 = 0.f;   // row 0
        float x1 = x0,       y1 = 0.f;   // row 1
        #pragma unroll 8
        for (int k = 0; k < 128; k += 2) {
            float wa = w_fc1[(size_t)k * 64 + o];
            float wb = w_fc1[(size_t)(k + 1) * 64 + o];
            float u0 = sPool[0][k], u1 = sPool[0][k + 1];
            float s0 = sPool[1][k], s1 = sPool[1][k + 1];
            x0 = fmaf(u0, wa, x0); y0 = fmaf(u1, wb, y0);
            x1 = fmaf(s0, wa, x1); y1 = fmaf(s1, wb, y1);
        }
        float h0 = fmaxf(x0 + y0, 0.f);
        float h1 = fmaxf(x1 + y1, 0.f);
        float wa = w_fc2[2 * o], wb = w_fc2[2 * o + 1];
        float q00 = h0 * wa, q01 = h0 * wb, q10 = h1 * wa, q11 = h1 * wb;
        #pragma unroll
        for (int d = 32; d; d >>= 1) {
            q00 += __shfl_xor(q00, d); q01 += __shfl_xor(q01, d);
            q10 += __shfl_xor(q10, d); q11 += __shfl_xor(q11, d);
        }
        if (lane == 0) {
            float bb0 = b_fc2[0], bb1 = b_fc2[1];
            float4 o4;
            o4.x = fmaxf(q00 + bb0, 0.f);
            o4.y = fmaxf(q01 + bb1, 0.f);
            o4.z = fmaxf(q10 + bb0, 0.f);
            o4.w = fmaxf(q11 + bb1, 0.f);
            *(float4*)&out[(size_t)b0 * 2] = o4;   // rows b0,b1 contiguous, 16B-aligned
        }
    }
}

extern "C" void kernel_launch(void* const* d_in, const int* in_sizes, int n_in,
                              void* d_out, int out_size, void* d_ws, size_t ws_size,
                              hipStream_t stream) {
    const float* cont_p = (const float*)d_in[0];
    const float* cont_c = (const float*)d_in[1];
    const int*   cat_p  = (const int*)d_in[2];
    const int*   cat_c  = (const int*)d_in[3];
    const int*   lens   = (const int*)d_in[4];
    const float* w_p1   = (const float*)d_in[5];
    const float* b_p1   = (const float*)d_in[6];
    const float* w_p2   = (const float*)d_in[7];
    const float* b_p2   = (const float*)d_in[8];
    const float* w_c1   = (const float*)d_in[9];
    const float* b_c1   = (const float*)d_in[10];
    const float* w_c2   = (const float*)d_in[11];
    const float* b_c2   = (const float*)d_in[12];
    const float* emb_g  = (const float*)d_in[13];
    const float* emb_k  = (const float*)d_in[14];
    const float* emb_pr = (const float*)d_in[15];
    const float* emb_j  = (const float*)d_in[16];
    const float* emb_r  = (const float*)d_in[17];
    const float* emb_pl = (const float*)d_in[18];
    const float* emb_a  = (const float*)d_in[19];
    const float* w_fc1  = (const float*)d_in[20];
    const float* b_fc1  = (const float*)d_in[21];
    const float* w_fc2  = (const float*)d_in[22];
    const float* b_fc2  = (const float*)d_in[23];
    float* out = (float*)d_out;

    hipLaunchKernelGGL(mlpreg_kernel, dim3(2048), dim3(BDIM), 0, stream,
                       cont_p, cont_c, cat_p, cat_c, lens,
                       w_p1, b_p1, w_p2, b_p2, w_c1, b_c1, w_c2, b_c2,
                       emb_g, emb_k, emb_pr, emb_j, emb_r, emb_pl, emb_a,
                       w_fc1, b_fc1, w_fc2, b_fc2, out);
}